// Round 1
// baseline (123.184 us; speedup 1.0000x reference)
//
#include <hip/hip_runtime.h>

// Problem constants (match reference)
#define TT 512   // sequence length
#define DD 256   // in_vocab_size
#define HH 256   // hidden_size

constexpr int TB = 4;  // t-rows per GEMM block

// Kernel 1: Bx[t][j]      = gamma[j]   * dot(x[t,:], B_c1[j,:])   for j in [0,256)
//           Bx[t][256+j]  = gamma[j]   * dot(x[t,:], B_c2[j,:])
// Layout: Bx is [T][2H] row-major so the scan reads/writes coalesced.
__global__ __launch_bounds__(256) void rtu_gemm(
    const float* __restrict__ x,
    const float* __restrict__ lamda,
    const float* __restrict__ B1,
    const float* __restrict__ B2,
    float* __restrict__ Bx) {
  __shared__ float xs[TB][DD];  // 4 KB
  const int t0 = blockIdx.x * TB;
  const int j = threadIdx.x;  // 0..255: handles columns j and 256+j

  // Stage x tile (TB x DD floats) into LDS with coalesced float4 loads.
  {
    const float4* xsrc = (const float4*)(x + t0 * DD);
    float4* xdst = (float4*)(&xs[0][0]);
    for (int i = j; i < TB * DD / 4; i += 256) xdst[i] = xsrc[i];
  }
  __syncthreads();

  const float4* b1 = (const float4*)(B1 + j * DD);
  const float4* b2 = (const float4*)(B2 + j * DD);
  const float4* xs4 = (const float4*)(&xs[0][0]);

  float acc1[TB];
  float acc2[TB];
#pragma unroll
  for (int tt = 0; tt < TB; ++tt) { acc1[tt] = 0.f; acc2[tt] = 0.f; }

#pragma unroll 8
  for (int k4 = 0; k4 < DD / 4; ++k4) {
    float4 v1 = b1[k4];
    float4 v2 = b2[k4];
#pragma unroll
    for (int tt = 0; tt < TB; ++tt) {
      float4 xv = xs4[tt * (DD / 4) + k4];  // broadcast LDS read (conflict-free)
      acc1[tt] = fmaf(v1.x, xv.x, acc1[tt]);
      acc1[tt] = fmaf(v1.y, xv.y, acc1[tt]);
      acc1[tt] = fmaf(v1.z, xv.z, acc1[tt]);
      acc1[tt] = fmaf(v1.w, xv.w, acc1[tt]);
      acc2[tt] = fmaf(v2.x, xv.x, acc2[tt]);
      acc2[tt] = fmaf(v2.y, xv.y, acc2[tt]);
      acc2[tt] = fmaf(v2.z, xv.z, acc2[tt]);
      acc2[tt] = fmaf(v2.w, xv.w, acc2[tt]);
    }
  }

  // Fold gamma into the projection (saves 2 mults/step in the sequential scan).
  const float la = lamda[j];
  const float y = __expf(-__expf(la));
  const float g = sqrtf(fmaxf(1.0f - y * y, 0.0f));

#pragma unroll
  for (int tt = 0; tt < TB; ++tt) {
    Bx[(t0 + tt) * (2 * HH) + j]      = acc1[tt] * g;
    Bx[(t0 + tt) * (2 * HH) + HH + j] = acc2[tt] * g;
  }
}

// Kernel 2: sequential rotation recurrence; thread j owns hidden unit j.
// out[t][j] = h1_t[j], out[t][256+j] = h2_t[j]  (== concat(h1n, h2n) per step)
__global__ __launch_bounds__(256) void rtu_scan(
    const float* __restrict__ lamda,
    const float* __restrict__ theta,
    const float* __restrict__ Bx,
    float* __restrict__ out) {
  const int j = threadIdx.x;
  const float la = lamda[j];
  const float y = __expf(-__expf(la));
  const float z = __expf(theta[j]);
  const float c = y * __cosf(z);
  const float s = y * __sinf(z);

  float h1 = 0.f, h2 = 0.f;
  const float* bp = Bx + j;
  float* op = out + j;

#pragma unroll 8
  for (int t = 0; t < TT; ++t) {
    const float b1 = bp[t * 2 * HH];        // gamma-prescaled bx1
    const float b2 = bp[t * 2 * HH + HH];   // gamma-prescaled bx2
    const float n1 = fmaf(c, h1, fmaf(-s, h2, b1));
    const float n2 = fmaf(c, h2, fmaf(s, h1, b2));
    h1 = n1;
    h2 = n2;
    op[t * 2 * HH] = h1;
    op[t * 2 * HH + HH] = h2;
  }
}

extern "C" void kernel_launch(void* const* d_in, const int* in_sizes, int n_in,
                              void* d_out, int out_size, void* d_ws, size_t ws_size,
                              hipStream_t stream) {
  const float* x     = (const float*)d_in[0];  // [T, D]
  const float* lamda = (const float*)d_in[1];  // [H]
  const float* theta = (const float*)d_in[2];  // [H]
  const float* B1    = (const float*)d_in[3];  // [H, D]
  const float* B2    = (const float*)d_in[4];  // [H, D]
  float* out = (float*)d_out;                  // [T, 2H]
  float* Bx = (float*)d_ws;                    // [T, 2H] scratch (512 KB)

  rtu_gemm<<<dim3(TT / TB), 256, 0, stream>>>(x, lamda, B1, B2, Bx);
  rtu_scan<<<1, 256, 0, stream>>>(lamda, theta, Bx, out);
}

// Round 2
// 93.233 us; speedup vs baseline: 1.3212x; 1.3212x over previous
//
#include <hip/hip_runtime.h>

// Problem constants (match reference)
#define TT 512   // sequence length
#define DD 256   // in_vocab_size
#define HH 256   // hidden_size
#define CC 64    // number of chunks (blocks) in the parallel scan
#define LL (TT / CC)  // 8 steps per chunk

// Per-unit recurrence coefficients. h = (h1 + i h2); step: h' = r h + g*bx,
// r = c + i s, c = y cos z, s = y sin z, y = exp(-exp(lamda)), z = exp(theta),
// g = sqrt(1 - y^2). Only concat(h1,h2) is observable output; all RTRL
// sensitivity state in the reference is dead code.
__device__ inline void coeffs(const float* __restrict__ lamda,
                              const float* __restrict__ theta, int j,
                              float& c, float& s, float& g) {
  const float y = __expf(-__expf(lamda[j]));
  const float z = __expf(theta[j]);
  c = y * __cosf(z);
  s = y * __sinf(z);
  g = sqrtf(fmaxf(1.0f - y * y, 0.0f));
}

// Kernel 1: per-chunk GEMM + local scan, fully register-resident.
// Block c handles t in [c*LL, (c+1)*LL). Thread j owns hidden unit j
// (columns j and HH+j). Writes uncorrected local scan to out and the
// chunk-end state to E. Bx is never materialized to memory.
__global__ __launch_bounds__(256) void rtu_chunk(
    const float* __restrict__ x, const float* __restrict__ lamda,
    const float* __restrict__ theta, const float* __restrict__ B1,
    const float* __restrict__ B2, float* __restrict__ out,
    float* __restrict__ E) {
  __shared__ float xs[LL][DD];  // 8 KB
  const int cidx = blockIdx.x;
  const int t0 = cidx * LL;
  const int j = threadIdx.x;

  // Stage this chunk's x rows into LDS (coalesced float4).
  {
    const float4* xsrc = (const float4*)(x + t0 * DD);
    float4* xdst = (float4*)(&xs[0][0]);
    for (int i = j; i < LL * DD / 4; i += 256) xdst[i] = xsrc[i];
  }
  __syncthreads();

  const float4* b1 = (const float4*)(B1 + j * DD);
  const float4* b2 = (const float4*)(B2 + j * DD);
  const float4* xs4 = (const float4*)(&xs[0][0]);

  float a1[LL], a2[LL];
#pragma unroll
  for (int tt = 0; tt < LL; ++tt) { a1[tt] = 0.f; a2[tt] = 0.f; }

#pragma unroll 8
  for (int k4 = 0; k4 < DD / 4; ++k4) {
    float4 v1 = b1[k4];
    float4 v2 = b2[k4];
#pragma unroll
    for (int tt = 0; tt < LL; ++tt) {
      float4 xv = xs4[tt * (DD / 4) + k4];  // LDS broadcast, conflict-free
      a1[tt] = fmaf(v1.x, xv.x, a1[tt]);
      a1[tt] = fmaf(v1.y, xv.y, a1[tt]);
      a1[tt] = fmaf(v1.z, xv.z, a1[tt]);
      a1[tt] = fmaf(v1.w, xv.w, a1[tt]);
      a2[tt] = fmaf(v2.x, xv.x, a2[tt]);
      a2[tt] = fmaf(v2.y, xv.y, a2[tt]);
      a2[tt] = fmaf(v2.z, xv.z, a2[tt]);
      a2[tt] = fmaf(v2.w, xv.w, a2[tt]);
    }
  }

  float c, s, g;
  coeffs(lamda, theta, j, c, s, g);

  // Local scan (carry-in = 0); uncorrected outputs + chunk-end state.
  float h1 = 0.f, h2 = 0.f;
#pragma unroll
  for (int tt = 0; tt < LL; ++tt) {
    const float bb1 = a1[tt] * g;
    const float bb2 = a2[tt] * g;
    const float n1 = fmaf(c, h1, fmaf(-s, h2, bb1));
    const float n2 = fmaf(c, h2, fmaf(s, h1, bb2));
    h1 = n1;
    h2 = n2;
    out[(t0 + tt) * (2 * HH) + j] = h1;
    out[(t0 + tt) * (2 * HH) + HH + j] = h2;
  }
  E[cidx * (2 * HH) + j] = h1;
  E[cidx * (2 * HH) + HH + j] = h2;
}

// Kernel 2: sequential composition over the CC chunk transitions (1 block).
// carry[c] = state entering chunk c; S' = r^LL * S + E[c].
// r^LL computed by complex squaring from (c,s) — matches the composed
// per-step recurrence exactly up to fp rounding.
__global__ __launch_bounds__(256) void rtu_combine(
    const float* __restrict__ lamda, const float* __restrict__ theta,
    const float* __restrict__ E, float* __restrict__ carry) {
  const int j = threadIdx.x;
  float c, s, g;
  coeffs(lamda, theta, j, c, s, g);
  float cl = c, sl = s;  // (c + i s)^LL, LL = 8 -> 3 squarings
#pragma unroll
  for (int q = 0; q < 3; ++q) {
    const float nc = cl * cl - sl * sl;
    const float ns = 2.f * cl * sl;
    cl = nc;
    sl = ns;
  }
  float S1 = 0.f, S2 = 0.f;
#pragma unroll 16
  for (int ci = 0; ci < CC; ++ci) {
    carry[ci * (2 * HH) + j] = S1;
    carry[ci * (2 * HH) + HH + j] = S2;
    const float E1 = E[ci * (2 * HH) + j];
    const float E2 = E[ci * (2 * HH) + HH + j];
    const float n1 = fmaf(cl, S1, fmaf(-sl, S2, E1));
    const float n2 = fmaf(cl, S2, fmaf(sl, S1, E2));
    S1 = n1;
    S2 = n2;
  }
}

// Kernel 3: in-place correction, out[t0+i] += r^(i+1) * carry[c]. Fully
// parallel across chunks; all loads independent (compiler prefetches).
__global__ __launch_bounds__(256) void rtu_correct(
    const float* __restrict__ lamda, const float* __restrict__ theta,
    const float* __restrict__ carry, float* __restrict__ out) {
  const int cidx = blockIdx.x;
  const int t0 = cidx * LL;
  const int j = threadIdx.x;
  float c, s, g;
  coeffs(lamda, theta, j, c, s, g);
  const float S1 = carry[cidx * (2 * HH) + j];
  const float S2 = carry[cidx * (2 * HH) + HH + j];
  float p1 = c, p2 = s;  // r^(i+1)
#pragma unroll
  for (int i = 0; i < LL; ++i) {
    const int t = t0 + i;
    const float o1 = out[t * (2 * HH) + j] + p1 * S1 - p2 * S2;
    const float o2 = out[t * (2 * HH) + HH + j] + p2 * S1 + p1 * S2;
    out[t * (2 * HH) + j] = o1;
    out[t * (2 * HH) + HH + j] = o2;
    const float np1 = p1 * c - p2 * s;
    const float np2 = p1 * s + p2 * c;
    p1 = np1;
    p2 = np2;
  }
}

extern "C" void kernel_launch(void* const* d_in, const int* in_sizes, int n_in,
                              void* d_out, int out_size, void* d_ws, size_t ws_size,
                              hipStream_t stream) {
  const float* x     = (const float*)d_in[0];  // [T, D]
  const float* lamda = (const float*)d_in[1];  // [H]
  const float* theta = (const float*)d_in[2];  // [H]
  const float* B1    = (const float*)d_in[3];  // [H, D]
  const float* B2    = (const float*)d_in[4];  // [H, D]
  float* out = (float*)d_out;                  // [T, 2H]

  float* E = (float*)d_ws;                     // [CC, 2H]  (128 KB)
  float* carry = E + CC * 2 * HH;              // [CC, 2H]  (128 KB)

  rtu_chunk<<<dim3(CC), 256, 0, stream>>>(x, lamda, theta, B1, B2, out, E);
  rtu_combine<<<1, 256, 0, stream>>>(lamda, theta, E, carry);
  rtu_correct<<<dim3(CC), 256, 0, stream>>>(lamda, theta, carry, out);
}

// Round 3
// 87.173 us; speedup vs baseline: 1.4131x; 1.0695x over previous
//
#include <hip/hip_runtime.h>

// Problem constants (match reference)
#define TT 512   // sequence length
#define DD 256   // in_vocab_size
#define HH 256   // hidden_size
#define CC 128   // number of chunks (blocks) in the parallel scan
#define LL (TT / CC)  // 4 steps per chunk

// Per-unit recurrence: h = (h1 + i h2); step: h' = r h + g*bx,
// r = c + i s, c = y cos z, s = y sin z, y = exp(-exp(lamda)), z = exp(theta),
// g = sqrt(1 - y^2). Only concat(h1,h2) is observable output; all RTRL
// sensitivity state in the reference is dead code (never reaches the output).
__device__ inline void coeffs(const float* __restrict__ lamda,
                              const float* __restrict__ theta, int j,
                              float& c, float& s, float& g) {
  const float y = __expf(-__expf(lamda[j]));
  const float z = __expf(theta[j]);
  c = y * __cosf(z);
  s = y * __sinf(z);
  g = sqrtf(fmaxf(1.0f - y * y, 0.0f));
}

// Kernel 1: per-chunk GEMM + local scan, fully register-resident.
// Block c handles t in [c*LL, (c+1)*LL). Thread j owns hidden unit j
// (columns j and HH+j). Writes uncorrected local scan to out and the
// chunk-end state to E. Bx is never materialized to memory.
__global__ __launch_bounds__(256) void rtu_chunk(
    const float* __restrict__ x, const float* __restrict__ lamda,
    const float* __restrict__ theta, const float* __restrict__ B1,
    const float* __restrict__ B2, float* __restrict__ out,
    float* __restrict__ E) {
  __shared__ float xs[LL][DD];  // 4 KB
  const int cidx = blockIdx.x;
  const int t0 = cidx * LL;
  const int j = threadIdx.x;

  // Stage this chunk's x rows into LDS: exactly one float4 per thread.
  {
    const float4* xsrc = (const float4*)(x + t0 * DD);
    ((float4*)(&xs[0][0]))[j] = xsrc[j];
  }
  __syncthreads();

  const float4* b1 = (const float4*)(B1 + j * DD);
  const float4* b2 = (const float4*)(B2 + j * DD);
  const float4* xs4 = (const float4*)(&xs[0][0]);

  float a1[LL], a2[LL];
#pragma unroll
  for (int tt = 0; tt < LL; ++tt) { a1[tt] = 0.f; a2[tt] = 0.f; }

#pragma unroll 8
  for (int k4 = 0; k4 < DD / 4; ++k4) {
    float4 v1 = b1[k4];
    float4 v2 = b2[k4];
#pragma unroll
    for (int tt = 0; tt < LL; ++tt) {
      float4 xv = xs4[tt * (DD / 4) + k4];  // LDS broadcast, conflict-free
      a1[tt] = fmaf(v1.x, xv.x, a1[tt]);
      a1[tt] = fmaf(v1.y, xv.y, a1[tt]);
      a1[tt] = fmaf(v1.z, xv.z, a1[tt]);
      a1[tt] = fmaf(v1.w, xv.w, a1[tt]);
      a2[tt] = fmaf(v2.x, xv.x, a2[tt]);
      a2[tt] = fmaf(v2.y, xv.y, a2[tt]);
      a2[tt] = fmaf(v2.z, xv.z, a2[tt]);
      a2[tt] = fmaf(v2.w, xv.w, a2[tt]);
    }
  }

  float c, s, g;
  coeffs(lamda, theta, j, c, s, g);

  // Local scan (carry-in = 0); uncorrected outputs + chunk-end state.
  float h1 = 0.f, h2 = 0.f;
#pragma unroll
  for (int tt = 0; tt < LL; ++tt) {
    const float bb1 = a1[tt] * g;
    const float bb2 = a2[tt] * g;
    const float n1 = fmaf(c, h1, fmaf(-s, h2, bb1));
    const float n2 = fmaf(c, h2, fmaf(s, h1, bb2));
    h1 = n1;
    h2 = n2;
    out[(t0 + tt) * (2 * HH) + j] = h1;
    out[(t0 + tt) * (2 * HH) + HH + j] = h2;
  }
  E[cidx * (2 * HH) + j] = h1;
  E[cidx * (2 * HH) + HH + j] = h2;
}

// Kernel 2: fused combine + correct. Block c redundantly computes its own
// carry S_c = sum_{ci<c} (r^LL)^{c-1-ci} E[ci] via a chained complex FMA
// (<=127 steps; loads independent, chain ~8 cyc/step), then applies
// out[t0+i] += r^(i+1) * S_c in place. No grid sync, no carry round-trip.
__global__ __launch_bounds__(256) void rtu_fixup(
    const float* __restrict__ lamda, const float* __restrict__ theta,
    const float* __restrict__ E, float* __restrict__ out) {
  const int cidx = blockIdx.x;
  if (cidx == 0) return;  // carry is zero; local scan already exact
  const int j = threadIdx.x;
  float c, s, g;
  coeffs(lamda, theta, j, c, s, g);

  // r^LL, LL = 4 -> 2 complex squarings (exact composition of the step op).
  float cl = c, sl = s;
#pragma unroll
  for (int q = 0; q < 2; ++q) {
    const float nc = cl * cl - sl * sl;
    const float ns = 2.f * cl * sl;
    cl = nc;
    sl = ns;
  }

  float S1 = 0.f, S2 = 0.f;
  const float* Ep = E + j;
#pragma unroll 8
  for (int ci = 0; ci < cidx; ++ci) {
    const float E1 = Ep[ci * (2 * HH)];
    const float E2 = Ep[ci * (2 * HH) + HH];
    const float n1 = fmaf(cl, S1, fmaf(-sl, S2, E1));
    const float n2 = fmaf(cl, S2, fmaf(sl, S1, E2));
    S1 = n1;
    S2 = n2;
  }

  const int t0 = cidx * LL;
  float p1 = c, p2 = s;  // r^(i+1)
#pragma unroll
  for (int i = 0; i < LL; ++i) {
    const int t = t0 + i;
    const float o1 = out[t * (2 * HH) + j] + p1 * S1 - p2 * S2;
    const float o2 = out[t * (2 * HH) + HH + j] + p2 * S1 + p1 * S2;
    out[t * (2 * HH) + j] = o1;
    out[t * (2 * HH) + HH + j] = o2;
    const float np1 = p1 * c - p2 * s;
    const float np2 = p1 * s + p2 * c;
    p1 = np1;
    p2 = np2;
  }
}

extern "C" void kernel_launch(void* const* d_in, const int* in_sizes, int n_in,
                              void* d_out, int out_size, void* d_ws, size_t ws_size,
                              hipStream_t stream) {
  const float* x     = (const float*)d_in[0];  // [T, D]
  const float* lamda = (const float*)d_in[1];  // [H]
  const float* theta = (const float*)d_in[2];  // [H]
  const float* B1    = (const float*)d_in[3];  // [H, D]
  const float* B2    = (const float*)d_in[4];  // [H, D]
  float* out = (float*)d_out;                  // [T, 2H]

  float* E = (float*)d_ws;                     // [CC, 2H] (256 KB)

  rtu_chunk<<<dim3(CC), 256, 0, stream>>>(x, lamda, theta, B1, B2, out, E);
  rtu_fixup<<<dim3(CC), 256, 0, stream>>>(lamda, theta, E, out);
}